// Round 4
// baseline (103.610 us; speedup 1.0000x reference)
//
#include <hip/hip_runtime.h>

// CenterLoss: loss = 0.5/B * (FF - 2*DOT + CC)
//   FF  = sum_i ||f_i||^2
//   DOT = sum_c sum_vec_c . newc_c
//   CC  = sum_c count_c * ||newc_c||^2
//   newc_c = count_c>0 ? 0.5*centers_c + 0.5*sum_vec_c/count_c : centers_c
// One pass over feats (134 MB) via counting-sort binning + per-class blocks.

#define DDIM 256
#define DDIM4 64
#define CHUNK 2048

__global__ __launch_bounds__(1024) void k0_zero(int* __restrict__ counts,
                                                float* __restrict__ scalars) {
    int t = threadIdx.x;
    counts[t] = 0;           // counts[0..1023]
    if (t < 4) scalars[t] = 0.f;
}

__global__ __launch_bounds__(256) void k1_hist(const int* __restrict__ labels,
                                               int* __restrict__ counts,
                                               int B, int C) {
    __shared__ int h[1024];
    for (int i = threadIdx.x; i < 1024; i += 256) h[i] = 0;
    __syncthreads();
    int stride = gridDim.x * 256;
    for (int i = blockIdx.x * 256 + threadIdx.x; i < B; i += stride)
        atomicAdd(&h[labels[i]], 1);
    __syncthreads();
    for (int i = threadIdx.x; i < C; i += 256) {
        int v = h[i];
        if (v) atomicAdd(&counts[i], v);
    }
}

// Single-block Hillis-Steele scan over <=1024 bins -> exclusive offsets + cursor copy.
__global__ __launch_bounds__(1024) void k2_scan(const int* __restrict__ counts,
                                                int* __restrict__ offsets,
                                                int* __restrict__ cursor, int C) {
    __shared__ int sc[1024];
    int t = threadIdx.x;
    int mine = (t < C) ? counts[t] : 0;
    sc[t] = mine;
    __syncthreads();
    for (int off = 1; off < 1024; off <<= 1) {
        int add = (t >= off) ? sc[t - off] : 0;
        __syncthreads();
        sc[t] += add;
        __syncthreads();
    }
    if (t < C) {
        int e = sc[t] - mine;   // exclusive prefix
        offsets[t] = e;
        cursor[t]  = e;
    }
}

__global__ __launch_bounds__(256) void k3_scatter(const int* __restrict__ labels,
                                                  int* __restrict__ cursor,
                                                  int* __restrict__ rowidx, int B) {
    int stride = gridDim.x * 256;
    for (int i = blockIdx.x * 256 + threadIdx.x; i < B; i += stride) {
        int c = labels[i];
        int pos = atomicAdd(&cursor[c], 1);
        rowidx[pos] = i;
    }
}

// One block per class. 4 waves; wave w sums rows w, w+4, ...; lane l holds float4 l.
__global__ __launch_bounds__(256) void k4_class(const float4* __restrict__ feats4,
                                                const float* __restrict__ centers,
                                                const int* __restrict__ rowidx,
                                                const int* __restrict__ counts,
                                                const int* __restrict__ offsets,
                                                float* __restrict__ scalars) {
    __shared__ int rows[CHUNK];
    __shared__ float comb[4 * DDIM];
    __shared__ float red[12];

    int c = blockIdx.x;
    int count = counts[c];
    int start = offsets[c];
    int t = threadIdx.x;
    int wave = t >> 6, lane = t & 63;

    float4 acc = make_float4(0.f, 0.f, 0.f, 0.f);
    float ff = 0.f;

    for (int cs = 0; cs < count; cs += CHUNK) {
        int n = min(CHUNK, count - cs);
        for (int i = t; i < n; i += 256) rows[i] = rowidx[start + cs + i];
        __syncthreads();
        int r = wave;
        // 4x unroll for memory-level parallelism (stride 4 per wave -> 16 rows/iter)
        for (; r + 12 < n; r += 16) {
            int r0 = rows[r], r1 = rows[r + 4], r2 = rows[r + 8], r3 = rows[r + 12];
            float4 v0 = feats4[r0 * DDIM4 + lane];
            float4 v1 = feats4[r1 * DDIM4 + lane];
            float4 v2 = feats4[r2 * DDIM4 + lane];
            float4 v3 = feats4[r3 * DDIM4 + lane];
            acc.x += v0.x; acc.y += v0.y; acc.z += v0.z; acc.w += v0.w;
            ff += v0.x*v0.x + v0.y*v0.y + v0.z*v0.z + v0.w*v0.w;
            acc.x += v1.x; acc.y += v1.y; acc.z += v1.z; acc.w += v1.w;
            ff += v1.x*v1.x + v1.y*v1.y + v1.z*v1.z + v1.w*v1.w;
            acc.x += v2.x; acc.y += v2.y; acc.z += v2.z; acc.w += v2.w;
            ff += v2.x*v2.x + v2.y*v2.y + v2.z*v2.z + v2.w*v2.w;
            acc.x += v3.x; acc.y += v3.y; acc.z += v3.z; acc.w += v3.w;
            ff += v3.x*v3.x + v3.y*v3.y + v3.z*v3.z + v3.w*v3.w;
        }
        for (; r < n; r += 4) {
            float4 v = feats4[rows[r] * DDIM4 + lane];
            acc.x += v.x; acc.y += v.y; acc.z += v.z; acc.w += v.w;
            ff += v.x*v.x + v.y*v.y + v.z*v.z + v.w*v.w;
        }
        __syncthreads();
    }

    // Combine the 4 wave-partials per dimension.
    comb[wave * DDIM + lane * 4 + 0] = acc.x;
    comb[wave * DDIM + lane * 4 + 1] = acc.y;
    comb[wave * DDIM + lane * 4 + 2] = acc.z;
    comb[wave * DDIM + lane * 4 + 3] = acc.w;
    __syncthreads();

    int d = t;  // thread t owns dimension d (DDIM == blockDim)
    float s  = comb[d] + comb[DDIM + d] + comb[2 * DDIM + d] + comb[3 * DDIM + d];
    float co = centers[c * DDIM + d];
    float nc = (count > 0) ? 0.5f * co + 0.5f * s / (float)count : co;
    float dotv = nc * s;                    // count==0 -> s==0 -> 0
    float ccv  = nc * nc * (float)count;    // count==0 -> 0

    // Block-reduce ff, dotv, ccv.
#pragma unroll
    for (int off = 32; off > 0; off >>= 1) {
        ff   += __shfl_down(ff, off);
        dotv += __shfl_down(dotv, off);
        ccv  += __shfl_down(ccv, off);
    }
    if (lane == 0) {
        red[wave * 3 + 0] = ff;
        red[wave * 3 + 1] = dotv;
        red[wave * 3 + 2] = ccv;
    }
    __syncthreads();
    if (t == 0) {
        float a = red[0] + red[3] + red[6] + red[9];
        float b = red[1] + red[4] + red[7] + red[10];
        float e = red[2] + red[5] + red[8] + red[11];
        atomicAdd(&scalars[0], a);
        atomicAdd(&scalars[1], b);
        atomicAdd(&scalars[2], e);
    }
}

__global__ void k5_final(const float* __restrict__ scalars, float* __restrict__ out, int B) {
    if (threadIdx.x == 0 && blockIdx.x == 0) {
        out[0] = 0.5f / (float)B * (scalars[0] - 2.f * scalars[1] + scalars[2]);
    }
}

extern "C" void kernel_launch(void* const* d_in, const int* in_sizes, int n_in,
                              void* d_out, int out_size, void* d_ws, size_t ws_size,
                              hipStream_t stream) {
    const float* feats   = (const float*)d_in[0];
    const float* centers = (const float*)d_in[1];
    const int*   labels  = (const int*)d_in[2];

    int B = in_sizes[2];              // 131072
    int Dv = in_sizes[0] / B;         // 256 (kernel assumes 256)
    int C = in_sizes[1] / Dv;         // 1000
    (void)Dv; (void)n_in; (void)ws_size;

    int* W = (int*)d_ws;
    int* counts  = W;                 // [1024]
    int* offsets = W + 1024;          // [1024]
    int* cursor  = W + 2048;          // [1024]
    float* scalars = (float*)(W + 3072); // [4] FF, DOT, CC
    int* rowidx  = W + 3072 + 16;     // [B]

    k0_zero<<<1, 1024, 0, stream>>>(counts, scalars);
    k1_hist<<<256, 256, 0, stream>>>(labels, counts, B, C);
    k2_scan<<<1, 1024, 0, stream>>>(counts, offsets, cursor, C);
    int sblocks = (B + 255) / 256;
    if (sblocks > 512) sblocks = 512;
    k3_scatter<<<sblocks, 256, 0, stream>>>(labels, cursor, rowidx, B);
    k4_class<<<C, 256, 0, stream>>>((const float4*)feats, centers, rowidx,
                                    counts, offsets, scalars);
    k5_final<<<1, 64, 0, stream>>>(scalars, (float*)d_out, B);
}